// Round 4
// baseline (262.876 us; speedup 1.0000x reference)
//
#include <hip/hip_runtime.h>
#include <hip/hip_bf16.h>
#include <math.h>

// ---------------------------------------------------------------------------
// B=1024, D_DATA=16384, D_LAT=256, N_GRID=256. Inputs f32.
// d_out = f32 slots; harness reads high u16 of each slot as bf16 -> store
// (float)__float2bfloat16(v) (proven R6).
//
// Structure (3 launches):
//   losses_kernel : 1024x512, contiguous chunks + unroll x4.
//   dist_kernel   : 256x256, dist tiles (diag = 0 -> barrier/flag slots) +
//                   fused Boruvka round-0 phase A into cmin buf0.
//   mst_kernel    : persistent 64x256. Boruvka rounds ONLY while ncomp>100
//                   (typically 2, bounded 3; R3 showed 9 rounds x
//                   [barrier+phaseB] = 58us of waiting). Then CONTRACT to a
//                   c x c matrix (c<=100) and finish with single-wave Prim in
//                   block 0 — zero barriers for the last ~30 merges. All MSTs
//                   share the same weight multiset, so contraction + plain
//                   weights is exact for the silhouette.
//
// Contract protocol (no extra full barriers beyond one):
//   - each block scans ITS OWN 16 rows -> LDS cmat[c][c] (dense comp ids via
//     redundant deterministic rank scan). No cross-block hazard.
//   - gcmat (c^2 <= 10000 u32 = 40KB) OVERLAYS dist rows 1008..1023 (64KB).
//     Only block 63 reads those rows (its scan), so block 63 inits gcmat
//     after its scan and release-stores a flag (diag slot (10,10)); other
//     blocks acquire-spin the flag before their atomicMin merge.
//   - one 64-arrival write-barrier (diag slot (11,11)), then block 0 loads
//     gcmat -> LDS and wave 0 runs Prim (c-1 steps, shfl-only reduction),
//     recording the remaining c-1 deaths. Tail: silhouette + final.
//   Diagonal slots are safe: dist[i][j] with j==i is only read when
//   comp[j]==comp[i] -> always skipped as a distance (R3 invariant).
//
// ws layout (floats):
//   [0..2047]    cmin buf0 (u64[1024])  init by losses
//   [2048..4095] cmin buf1 (u64[1024])  init by losses
//   [4096..6143] cmin buf2 (u64[1024])  init by mst start; sq overlays start
//   [6144..8191] partials (recon 1024 | kl 1024)
//   [8192..]     dist 1024x1024 (4 MB); diag(r,r) r=1..9 round barriers,
//                (10,10) flag, (11,11) write barrier; rows 1008.. = gcmat.
// ---------------------------------------------------------------------------

#define NBLK 1024
#define PBLK 64
#define CMAX 100

__device__ __forceinline__ float sub2(const float4 a, const float4 b) {
  const float dx = a.x - b.x, dy = a.y - b.y, dz = a.z - b.z, dw = a.w - b.w;
  return dx * dx + dy * dy + dz * dz + dw * dw;
}

__global__ __launch_bounds__(512) void losses_kernel(const float4* __restrict__ rx,
                                                     const float4* __restrict__ x,
                                                     const float4* __restrict__ mu,
                                                     const float4* __restrict__ lv,
                                                     const float* __restrict__ z,
                                                     float* __restrict__ partials,
                                                     float* __restrict__ sq,
                                                     unsigned long long* __restrict__ cmin01) {
  const int t = threadIdx.x;
  const int b = blockIdx.x;
  if (b == 0) {
    for (int v = t; v < 2048; v += 512) cmin01[v] = ~0ull;
  }
  const int base = b * 4096 + t;
  float rs = 0.f;
#pragma unroll
  for (int k = 0; k < 2; ++k) {
    const int i0 = base + k * 2048;
    const float4 a0 = rx[i0],        c0 = x[i0];
    const float4 a1 = rx[i0 + 512],  c1 = x[i0 + 512];
    const float4 a2 = rx[i0 + 1024], c2 = x[i0 + 1024];
    const float4 a3 = rx[i0 + 1536], c3 = x[i0 + 1536];
    rs += sub2(a0, c0) + sub2(a1, c1) + sub2(a2, c2) + sub2(a3, c3);
  }
  float ks = 0.f;
  const int gid = b * 512 + t;
  if (gid < 65536) {
    const float4 m = mu[gid], l = lv[gid];
    ks += 1.f + l.x - m.x * m.x - __expf(l.x);
    ks += 1.f + l.y - m.y * m.y - __expf(l.y);
    ks += 1.f + l.z - m.z * m.z - __expf(l.z);
    ks += 1.f + l.w - m.w * m.w - __expf(l.w);
  }
#pragma unroll
  for (int off = 32; off; off >>= 1) {
    rs += __shfl_xor(rs, off);
    ks += __shfl_xor(ks, off);
  }
  __shared__ float red[16];
  if ((t & 63) == 0) { red[t >> 6] = rs; red[8 + (t >> 6)] = ks; }
  __syncthreads();
  if (t == 0) {
    float a = 0.f, c = 0.f;
#pragma unroll
    for (int w = 0; w < 8; ++w) { a += red[w]; c += red[8 + w]; }
    partials[b] = a;
    partials[NBLK + b] = c;
  }
  if (b < 128) {
    const int lane = t & 63;
    const int row = b * 8 + (t >> 6);
    const float4 v = ((const float4*)(z + row * 256))[lane];
    float s = v.x * v.x + v.y * v.y + v.z * v.z + v.w * v.w;
#pragma unroll
    for (int off = 32; off; off >>= 1) s += __shfl_xor(s, off);
    if (lane == 0) sq[row] = s;
  }
}

__global__ __launch_bounds__(256) void dist_kernel(const float* __restrict__ z,
                                                   const float* __restrict__ sq,
                                                   float* __restrict__ dist,
                                                   unsigned long long* __restrict__ cmin0) {
  __shared__ float A[64][68];
  __shared__ float Bs[64][68];
  const int i0 = (blockIdx.x >> 4) * 64, j0 = (blockIdx.x & 15) * 64;
  const int t = threadIdx.x;
  const int tx = t & 15;
  const int ty = t >> 4;
  float acc[4][4] = {};
  for (int k0 = 0; k0 < 256; k0 += 64) {
    __syncthreads();
#pragma unroll
    for (int it = 0; it < 4; ++it) {
      int lin = it * 256 + t;
      int row = lin >> 4, q = lin & 15;
      *(float4*)&A[row][q * 4]  = *(const float4*)(z + (i0 + row) * 256 + k0 + q * 4);
      *(float4*)&Bs[row][q * 4] = *(const float4*)(z + (j0 + row) * 256 + k0 + q * 4);
    }
    __syncthreads();
#pragma unroll 4
    for (int k = 0; k < 64; k += 4) {
      float4 av[4], bv[4];
#pragma unroll
      for (int rr = 0; rr < 4; ++rr) av[rr] = *(const float4*)&A[ty + 16 * rr][k];
#pragma unroll
      for (int cc = 0; cc < 4; ++cc) bv[cc] = *(const float4*)&Bs[tx + 16 * cc][k];
#pragma unroll
      for (int rr = 0; rr < 4; ++rr)
#pragma unroll
        for (int cc = 0; cc < 4; ++cc) {
          acc[rr][cc] += av[rr].x * bv[cc].x;
          acc[rr][cc] += av[rr].y * bv[cc].y;
          acc[rr][cc] += av[rr].z * bv[cc].z;
          acc[rr][cc] += av[rr].w * bv[cc].w;
        }
    }
  }
  unsigned long long rowbest[4] = {~0ull, ~0ull, ~0ull, ~0ull};
#pragma unroll
  for (int rr = 0; rr < 4; ++rr) {
    const int i = i0 + ty + 16 * rr;
    const float sqi = sq[i];
#pragma unroll
    for (int cc = 0; cc < 4; ++cc) {
      const int j = j0 + tx + 16 * cc;
      const float d2 = sqi + sq[j] - 2.f * acc[rr][cc];
      const float d = sqrtf(fmaxf(d2, 0.f) + 1e-12f);
      dist[i * 1024 + j] = (j == i) ? 0.f : d;
      if (j != i) {
        const int lo = i < j ? i : j;
        const int hi = i + j - lo;
        const unsigned long long key =
            ((unsigned long long)__float_as_uint(d) << 32)
          | (unsigned long long)((lo << 10) | hi);
        if (key < rowbest[rr]) rowbest[rr] = key;
      }
    }
  }
#pragma unroll
  for (int rr = 0; rr < 4; ++rr) {
    unsigned long long best = rowbest[rr];
#pragma unroll
    for (int off = 8; off; off >>= 1) {
      const unsigned int blo = __shfl_xor((unsigned int)best, off);
      const unsigned int bhi = __shfl_xor((unsigned int)(best >> 32), off);
      const unsigned long long o = ((unsigned long long)bhi << 32) | blo;
      if (o < best) best = o;
    }
    if (tx == 0) {
      unsigned long long* p = &cmin0[i0 + ty + 16 * rr];
      const unsigned long long cur =
          __hip_atomic_load(p, __ATOMIC_RELAXED, __HIP_MEMORY_SCOPE_AGENT);
      if (best < cur) atomicMin(p, best);
    }
  }
}

__device__ __forceinline__ int phase_b_dev(const unsigned long long* __restrict__ cbuf,
                                           int* scomp, unsigned long long* cl,
                                           int* pnew, int* sred,
                                           bool record, float* sdeaths, int* scnt) {
  const int t = threadIdx.x;
  for (int v = t; v < 1024; v += 256)
    cl[v] = __hip_atomic_load(&cbuf[v], __ATOMIC_RELAXED, __HIP_MEMORY_SCOPE_AGENT);
  if (t == 0) sred[0] = 0;
  __syncthreads();
  for (int v = t; v < 1024; v += 256) {
    int parent = scomp[v];
    if (parent == v) {
      const unsigned long long key = cl[v];
      if (key != ~0ull) {
        const int lo = (int)((key >> 10) & 1023), hi = (int)(key & 1023);
        const int clo = scomp[lo], chi = scomp[hi];
        const int other = (clo == v) ? chi : clo;
        const bool mutual = (cl[other] == key);
        if (record && (!mutual || v < other)) {
          const int pos = atomicAdd(scnt, 1);
          sdeaths[pos] = __uint_as_float((unsigned int)(key >> 32));
        }
        parent = (mutual && v < other) ? v : other;
      }
    }
    pnew[v] = parent;
  }
  __syncthreads();
#pragma unroll
  for (int it = 0; it < 2; ++it) {
    int q0 = pnew[pnew[t]];
    int q1 = pnew[pnew[t + 256]];
    int q2 = pnew[pnew[t + 512]];
    int q3 = pnew[pnew[t + 768]];
    __syncthreads();
    pnew[t] = q0; pnew[t + 256] = q1; pnew[t + 512] = q2; pnew[t + 768] = q3;
    __syncthreads();
  }
  int nroots = 0;
#pragma unroll
  for (int q = 0; q < 4; ++q) {
    const int v = t + q * 256;
    int p = pnew[v];
    while (p != pnew[p]) p = pnew[p];
    scomp[v] = p;
    if (p == v) ++nroots;
  }
  atomicAdd(&sred[0], nroots);
  __syncthreads();
  return sred[0];
}

__global__ __launch_bounds__(256) void mst_kernel(float* __restrict__ dist,
                                                  unsigned long long* __restrict__ cminb,
                                                  const float* __restrict__ partials,
                                                  float* __restrict__ out) {
  __shared__ int scomp[1024];
  __shared__ int pnew[1024];
  __shared__ unsigned long long cl[1024];
  __shared__ unsigned int cmat[CMAX * CMAX];   // 40 KB
  __shared__ float sdeaths[1023];
  __shared__ int sred[2];
  __shared__ float redf[12];
  const int t = threadIdx.x;
  const int b = blockIdx.x;
  const bool rec = (b == 0);

  for (int v = t; v < 1024; v += 256) scomp[v] = v;
  if (t == 0) sred[1] = 0;
  if (t < 16)
    __hip_atomic_store(&cminb[2048 + b * 16 + t], ~0ull,
                       __ATOMIC_RELAXED, __HIP_MEMORY_SCOPE_AGENT);
  __syncthreads();

  int ncomp = phase_b_dev(cminb, scomp, cl, pnew, sred, rec, sdeaths, &sred[1]);

  const int lane = t & 63;
  const int w = t >> 6;
  // ---- Boruvka rounds only while ncomp > CMAX (typically 2, max ~3) ----
  for (int r = 1; r < 10 && ncomp > CMAX; ++r) {
    unsigned long long* cbuf = cminb + (r % 3) * 1024;
#pragma unroll
    for (int q = 0; q < 4; ++q) {
      const int i = b * 16 + w * 4 + q;
      const int ci = scomp[i];
      const float* row = dist + i * 1024;
      unsigned long long best = ~0ull;
#pragma unroll
      for (int k = 0; k < 4; ++k) {
        const int j0 = lane * 4 + k * 256;
        const float4 d4 = *(const float4*)(row + j0);
        const int4 c4 = *(const int4*)(&scomp[j0]);
        const float dv[4] = {d4.x, d4.y, d4.z, d4.w};
        const int cv[4] = {c4.x, c4.y, c4.z, c4.w};
#pragma unroll
        for (int c = 0; c < 4; ++c) {
          if (cv[c] != ci) {
            const int j = j0 + c;
            const int lo = i < j ? i : j;
            const int hi = i + j - lo;
            const unsigned long long key =
                ((unsigned long long)__float_as_uint(dv[c]) << 32)
              | (unsigned long long)((lo << 10) | hi);
            if (key < best) best = key;
          }
        }
      }
#pragma unroll
      for (int off = 32; off; off >>= 1) {
        const unsigned int blo = __shfl_xor((unsigned int)best, off);
        const unsigned int bhi = __shfl_xor((unsigned int)(best >> 32), off);
        const unsigned long long o = ((unsigned long long)bhi << 32) | blo;
        if (o < best) best = o;
      }
      if (lane == 0 && best != ~0ull) {
        const unsigned long long cur =
            __hip_atomic_load(&cbuf[ci], __ATOMIC_RELAXED, __HIP_MEMORY_SCOPE_AGENT);
        if (best < cur) atomicMin(&cbuf[ci], best);
      }
    }
    int* ctrp = (int*)(dist + (size_t)r * 1025);
    __syncthreads();
    if (t == 0) {
      __hip_atomic_fetch_add(ctrp, 1, __ATOMIC_ACQ_REL, __HIP_MEMORY_SCOPE_AGENT);
      while (__hip_atomic_load(ctrp, __ATOMIC_ACQUIRE, __HIP_MEMORY_SCOPE_AGENT) < PBLK)
        __builtin_amdgcn_s_sleep(2);
    }
    __syncthreads();
    if (t < 16)
      __hip_atomic_store(&cminb[((r - 1) % 3) * 1024 + b * 16 + t], ~0ull,
                         __ATOMIC_RELAXED, __HIP_MEMORY_SCOPE_AGENT);
    ncomp = phase_b_dev(cbuf, scomp, cl, pnew, sred, rec, sdeaths, &sred[1]);
  }

  unsigned int* gcm = (unsigned int*)(dist + 1008 * 1024);   // overlay, 40KB used
  int* flag = (int*)(dist + (size_t)10 * 1025);
  int* wbar = (int*)(dist + (size_t)11 * 1025);

  if (ncomp > 1) {
    const int c = ncomp;
    // ---- dense rank (redundant, deterministic): itmp = inclusive scan ----
    int* itmp = (int*)cl;                       // 2048 ints
    for (int v = t; v < 1024; v += 256) itmp[v] = (scomp[v] == v) ? 1 : 0;
    __syncthreads();
    for (int off = 1; off < 1024; off <<= 1) {
      int vals[4];
#pragma unroll
      for (int q = 0; q < 4; ++q) {
        const int v = t + q * 256;
        vals[q] = itmp[v] + ((v >= off) ? itmp[v - off] : 0);
      }
      __syncthreads();
#pragma unroll
      for (int q = 0; q < 4; ++q) itmp[t + q * 256] = vals[q];
      __syncthreads();
    }
    for (int v = t; v < 1024; v += 256) pnew[v] = itmp[scomp[v]] - 1;  // dcomp
    // ---- init LDS cmat, scan own 16 rows ----
    for (int e = t; e < c * c; e += 256) cmat[e] = ~0u;
    __syncthreads();
#pragma unroll
    for (int q = 0; q < 4; ++q) {
      const int i = b * 16 + w * 4 + q;
      const int a = pnew[i];
      const float* row = dist + i * 1024;
#pragma unroll
      for (int k = 0; k < 4; ++k) {
        const int j0 = lane * 4 + k * 256;
        const float4 d4 = *(const float4*)(row + j0);
        const int4 c4 = *(const int4*)(&pnew[j0]);
        const float dv[4] = {d4.x, d4.y, d4.z, d4.w};
        const int cv[4] = {c4.x, c4.y, c4.z, c4.w};
#pragma unroll
        for (int cc = 0; cc < 4; ++cc) {
          if (cv[cc] != a) {
            const unsigned int u = __float_as_uint(dv[cc]);
            const int idx = a * c + cv[cc];
            if (u < cmat[idx]) atomicMin(&cmat[idx], u);
          }
        }
      }
    }
    __syncthreads();
    // ---- block 63 inits gcmat (its rows are now consumed), sets flag ----
    if (b == PBLK - 1) {
      for (int e = t; e < c * c; e += 256) gcm[e] = ~0u;
      __syncthreads();
      __threadfence();
      if (t == 0)
        __hip_atomic_store(flag, 1, __ATOMIC_RELEASE, __HIP_MEMORY_SCOPE_AGENT);
    }
    if (t == 0) {
      while (__hip_atomic_load(flag, __ATOMIC_ACQUIRE, __HIP_MEMORY_SCOPE_AGENT) == 0)
        __builtin_amdgcn_s_sleep(1);
    }
    __syncthreads();
    // ---- merge local cmat -> gcmat ----
    for (int e = t; e < c * c; e += 256) {
      const unsigned int u = cmat[e];
      if (u != ~0u) {
        const unsigned int cur =
            __hip_atomic_load(&gcm[e], __ATOMIC_RELAXED, __HIP_MEMORY_SCOPE_AGENT);
        if (u < cur) atomicMin(&gcm[e], u);
      }
    }
    __threadfence();
    __syncthreads();
    if (t == 0) {
      __hip_atomic_fetch_add(wbar, 1, __ATOMIC_ACQ_REL, __HIP_MEMORY_SCOPE_AGENT);
      while (__hip_atomic_load(wbar, __ATOMIC_ACQUIRE, __HIP_MEMORY_SCOPE_AGENT) < PBLK)
        __builtin_amdgcn_s_sleep(1);
    }
    __syncthreads();
    if (b != 0) return;
    // ---- block 0: gcmat -> LDS, wave 0 runs Prim (c-1 steps) ----
    for (int e = t; e < c * c; e += 256) cmat[e] = gcm[e];
    __syncthreads();
    const int base = sred[1];                  // deaths recorded so far
    if (t < 64) {
      const int e0 = lane, e1 = 64 + lane;
      unsigned int md0 = (e0 < c && e0 != 0) ? cmat[e0] : ~0u;   // row 0
      unsigned int md1 = (e1 < c) ? cmat[e1] : ~0u;
      for (int step = 0; step < c - 1; ++step) {
        unsigned long long k0 = ((unsigned long long)md0 << 32) | (unsigned int)e0;
        unsigned long long k1 = (e1 < c) ? (((unsigned long long)md1 << 32) | (unsigned int)e1)
                                         : ~0ull;
        unsigned long long best = k0 < k1 ? k0 : k1;
#pragma unroll
        for (int off = 32; off; off >>= 1) {
          const unsigned int blo = __shfl_xor((unsigned int)best, off);
          const unsigned int bhi = __shfl_xor((unsigned int)(best >> 32), off);
          const unsigned long long o = ((unsigned long long)bhi << 32) | blo;
          if (o < best) best = o;
        }
        const unsigned int wb = (unsigned int)(best >> 32);
        const int bc = (int)(best & 0xffffffffu);
        if (lane == 0) sdeaths[base + step] = __uint_as_float(wb);
        if (e0 == bc) md0 = ~0u;
        if (e1 == bc) md1 = ~0u;
        if (e0 < c && md0 != ~0u) {
          const unsigned int nv = cmat[bc * c + e0];
          if (nv < md0) md0 = nv;
        }
        if (e1 < c && md1 != ~0u) {
          const unsigned int nv = cmat[bc * c + e1];
          if (nv < md1) md1 = nv;
        }
      }
    }
    __syncthreads();
  } else if (b != 0) {
    return;
  }

  // ---------------- tail: silhouette + final (block 0 only) ----------------
  float lmax = 0.f, lsum = 0.f;
  for (int v = t; v < 1023; v += 256) {
    const float d = sdeaths[v];
    lmax = fmaxf(lmax, d);
    lsum += d;
  }
#pragma unroll
  for (int off = 32; off; off >>= 1) {
    lmax = fmaxf(lmax, __shfl_xor(lmax, off));
    lsum += __shfl_xor(lsum, off);
  }
  if ((t & 63) == 0) { redf[t >> 6] = lmax; redf[4 + (t >> 6)] = lsum; }
  __syncthreads();
  const float tmax = fmaxf(fmaxf(redf[0], redf[1]), fmaxf(redf[2], redf[3]));
  const float wsum = redf[4] + redf[5] + redf[6] + redf[7];
  const float tt = (float)t * (1.0f / 255.0f) * tmax;
  float acc = 0.f;
  for (int j = 0; j < 1023; ++j) {
    const float dj = sdeaths[j];
    acc += dj * fmaxf(fminf(tt, dj - tt), 0.f);
  }
  float phi = acc / (wsum + 1e-12f);
  float rs = 0.f, ks = 0.f;
  for (int v = t; v < 1024; v += 256) { rs += partials[v]; ks += partials[1024 + v]; }
#pragma unroll
  for (int off = 32; off; off >>= 1) {
    phi += __shfl_xor(phi, off);
    rs += __shfl_xor(rs, off);
    ks += __shfl_xor(ks, off);
  }
  __syncthreads();
  if ((t & 63) == 0) { redf[t >> 6] = phi; redf[4 + (t >> 6)] = rs; redf[8 + (t >> 6)] = ks; }
  __syncthreads();
  if (t == 0) {
    const float topo = (redf[0] + redf[1] + redf[2] + redf[3]) * (1.f / 256.f);
    const float recon = (redf[4] + redf[5] + redf[6] + redf[7]) * (1.f / 16777216.f);
    const float kl = -0.5f * (redf[8] + redf[9] + redf[10] + redf[11]) * (1.f / 262144.f);
    const float total = recon + 0.1f * kl + 0.5f * topo;
    out[0] = (float)__float2bfloat16(total);
    out[1] = (float)__float2bfloat16(recon);
    out[2] = (float)__float2bfloat16(kl);
    out[3] = (float)__float2bfloat16(topo);
  }
}

extern "C" void kernel_launch(void* const* d_in, const int* in_sizes, int n_in,
                              void* d_out, int out_size, void* d_ws, size_t ws_size,
                              hipStream_t stream) {
  const float* rx = (const float*)d_in[0];
  const float* x  = (const float*)d_in[1];
  const float* mu = (const float*)d_in[2];
  const float* lv = (const float*)d_in[3];
  const float* z  = (const float*)d_in[4];

  float* wsf = (float*)d_ws;
  unsigned long long* cminb = (unsigned long long*)wsf;    // 3 x u64[1024]
  float* sq       = wsf + 4096;                            // overlays cmin buf2
  float* partials = wsf + 6144;                            // 2048 floats
  float* dist     = wsf + 8192;                            // 4 MB
  float* out      = (float*)d_out;

  losses_kernel<<<NBLK, 512, 0, stream>>>((const float4*)rx, (const float4*)x,
                                          (const float4*)mu, (const float4*)lv,
                                          z, partials, sq, cminb);
  dist_kernel<<<256, 256, 0, stream>>>(z, sq, dist, cminb);
  mst_kernel<<<PBLK, 256, 0, stream>>>(dist, cminb, partials, out);
}

// Round 5
// 226.195 us; speedup vs baseline: 1.1622x; 1.1622x over previous
//
#include <hip/hip_runtime.h>
#include <hip/hip_bf16.h>
#include <math.h>

// ---------------------------------------------------------------------------
// B=1024, D_DATA=16384, D_LAT=256, N_GRID=256. Inputs f32.
// d_out = f32 slots; harness reads high u16 of each slot as bf16 -> store
// (float)__float2bfloat16(v) (proven R6).
//
// Structure (3 launches) — R3 structure (proven 58us mst) + slot barrier:
//   losses_kernel : 1024x512, contiguous chunks + unroll x4.
//   dist_kernel   : 256x256, dist tiles (diag = 0 -> slot-barrier cells) +
//                   fused Boruvka round-0 phase A into cmin buf0.
//   mst_kernel    : persistent 64x256, Boruvka to ncomp==1. comp in LDS per
//                   block, phase B redundant per block (deterministic).
//                   BARRIER (new): arrive = per-block RELEASE STORE of round r
//                   into its OWN LLC line (dist diag (16b+1,16b+1)); detect =
//                   wave 0 polls all 64 slots in one vector load + __all.
//                   R3/R4 showed 64 fetch_adds to ONE line cost ~4-5us/round
//                   (RMW serialization); parallel stores + gather-poll avoid
//                   both serial RMW and single-thread spin.
//                   R4's contraction REVERTED: its serialized LLC merge loop
//                   (load->cmp->atomicMin dependent chain) cost more than the
//                   barriers it removed (91us vs 58us).
//
// ws layout (floats):
//   [0..2047]    cmin buf0 (u64[1024])  init by losses
//   [2048..4095] cmin buf1 (u64[1024])  init by losses
//   [4096..6143] cmin buf2 (u64[1024])  init by mst start; sq overlays start
//   [6144..8191] partials (recon 1024 | kl 1024)
//   [8192..]     dist 1024x1024 (4 MB); diag (16b+1,16b+1) = barrier slots
//                (zeroed each iter by dist_kernel; never read as distances:
//                phase A skips comp[j]==comp[i], i.e. j==i)
// ---------------------------------------------------------------------------

#define NBLK 1024
#define PBLK 64

__device__ __forceinline__ float sub2(const float4 a, const float4 b) {
  const float dx = a.x - b.x, dy = a.y - b.y, dz = a.z - b.z, dw = a.w - b.w;
  return dx * dx + dy * dy + dz * dz + dw * dw;
}

__global__ __launch_bounds__(512) void losses_kernel(const float4* __restrict__ rx,
                                                     const float4* __restrict__ x,
                                                     const float4* __restrict__ mu,
                                                     const float4* __restrict__ lv,
                                                     const float* __restrict__ z,
                                                     float* __restrict__ partials,
                                                     float* __restrict__ sq,
                                                     unsigned long long* __restrict__ cmin01) {
  const int t = threadIdx.x;
  const int b = blockIdx.x;
  if (b == 0) {
    for (int v = t; v < 2048; v += 512) cmin01[v] = ~0ull;
  }
  const int base = b * 4096 + t;
  float rs = 0.f;
#pragma unroll
  for (int k = 0; k < 2; ++k) {
    const int i0 = base + k * 2048;
    const float4 a0 = rx[i0],        c0 = x[i0];
    const float4 a1 = rx[i0 + 512],  c1 = x[i0 + 512];
    const float4 a2 = rx[i0 + 1024], c2 = x[i0 + 1024];
    const float4 a3 = rx[i0 + 1536], c3 = x[i0 + 1536];
    rs += sub2(a0, c0) + sub2(a1, c1) + sub2(a2, c2) + sub2(a3, c3);
  }
  float ks = 0.f;
  const int gid = b * 512 + t;
  if (gid < 65536) {
    const float4 m = mu[gid], l = lv[gid];
    ks += 1.f + l.x - m.x * m.x - __expf(l.x);
    ks += 1.f + l.y - m.y * m.y - __expf(l.y);
    ks += 1.f + l.z - m.z * m.z - __expf(l.z);
    ks += 1.f + l.w - m.w * m.w - __expf(l.w);
  }
#pragma unroll
  for (int off = 32; off; off >>= 1) {
    rs += __shfl_xor(rs, off);
    ks += __shfl_xor(ks, off);
  }
  __shared__ float red[16];
  if ((t & 63) == 0) { red[t >> 6] = rs; red[8 + (t >> 6)] = ks; }
  __syncthreads();
  if (t == 0) {
    float a = 0.f, c = 0.f;
#pragma unroll
    for (int w = 0; w < 8; ++w) { a += red[w]; c += red[8 + w]; }
    partials[b] = a;
    partials[NBLK + b] = c;
  }
  if (b < 128) {
    const int lane = t & 63;
    const int row = b * 8 + (t >> 6);
    const float4 v = ((const float4*)(z + row * 256))[lane];
    float s = v.x * v.x + v.y * v.y + v.z * v.z + v.w * v.w;
#pragma unroll
    for (int off = 32; off; off >>= 1) s += __shfl_xor(s, off);
    if (lane == 0) sq[row] = s;
  }
}

__global__ __launch_bounds__(256) void dist_kernel(const float* __restrict__ z,
                                                   const float* __restrict__ sq,
                                                   float* __restrict__ dist,
                                                   unsigned long long* __restrict__ cmin0) {
  __shared__ float A[64][68];
  __shared__ float Bs[64][68];
  const int i0 = (blockIdx.x >> 4) * 64, j0 = (blockIdx.x & 15) * 64;
  const int t = threadIdx.x;
  const int tx = t & 15;
  const int ty = t >> 4;
  float acc[4][4] = {};
  for (int k0 = 0; k0 < 256; k0 += 64) {
    __syncthreads();
#pragma unroll
    for (int it = 0; it < 4; ++it) {
      int lin = it * 256 + t;
      int row = lin >> 4, q = lin & 15;
      *(float4*)&A[row][q * 4]  = *(const float4*)(z + (i0 + row) * 256 + k0 + q * 4);
      *(float4*)&Bs[row][q * 4] = *(const float4*)(z + (j0 + row) * 256 + k0 + q * 4);
    }
    __syncthreads();
#pragma unroll 4
    for (int k = 0; k < 64; k += 4) {
      float4 av[4], bv[4];
#pragma unroll
      for (int rr = 0; rr < 4; ++rr) av[rr] = *(const float4*)&A[ty + 16 * rr][k];
#pragma unroll
      for (int cc = 0; cc < 4; ++cc) bv[cc] = *(const float4*)&Bs[tx + 16 * cc][k];
#pragma unroll
      for (int rr = 0; rr < 4; ++rr)
#pragma unroll
        for (int cc = 0; cc < 4; ++cc) {
          acc[rr][cc] += av[rr].x * bv[cc].x;
          acc[rr][cc] += av[rr].y * bv[cc].y;
          acc[rr][cc] += av[rr].z * bv[cc].z;
          acc[rr][cc] += av[rr].w * bv[cc].w;
        }
    }
  }
  unsigned long long rowbest[4] = {~0ull, ~0ull, ~0ull, ~0ull};
#pragma unroll
  for (int rr = 0; rr < 4; ++rr) {
    const int i = i0 + ty + 16 * rr;
    const float sqi = sq[i];
#pragma unroll
    for (int cc = 0; cc < 4; ++cc) {
      const int j = j0 + tx + 16 * cc;
      const float d2 = sqi + sq[j] - 2.f * acc[rr][cc];
      const float d = sqrtf(fmaxf(d2, 0.f) + 1e-12f);
      dist[i * 1024 + j] = (j == i) ? 0.f : d;
      if (j != i) {
        const int lo = i < j ? i : j;
        const int hi = i + j - lo;
        const unsigned long long key =
            ((unsigned long long)__float_as_uint(d) << 32)
          | (unsigned long long)((lo << 10) | hi);
        if (key < rowbest[rr]) rowbest[rr] = key;
      }
    }
  }
#pragma unroll
  for (int rr = 0; rr < 4; ++rr) {
    unsigned long long best = rowbest[rr];
#pragma unroll
    for (int off = 8; off; off >>= 1) {
      const unsigned int blo = __shfl_xor((unsigned int)best, off);
      const unsigned int bhi = __shfl_xor((unsigned int)(best >> 32), off);
      const unsigned long long o = ((unsigned long long)bhi << 32) | blo;
      if (o < best) best = o;
    }
    if (tx == 0) {
      unsigned long long* p = &cmin0[i0 + ty + 16 * rr];
      const unsigned long long cur =
          __hip_atomic_load(p, __ATOMIC_RELAXED, __HIP_MEMORY_SCOPE_AGENT);
      if (best < cur) atomicMin(p, best);
    }
  }
}

__device__ __forceinline__ int phase_b_dev(const unsigned long long* __restrict__ cbuf,
                                           int* scomp, unsigned long long* cl,
                                           int* pnew, int* sred,
                                           bool record, float* sdeaths, int* scnt) {
  const int t = threadIdx.x;
  for (int v = t; v < 1024; v += 256)
    cl[v] = __hip_atomic_load(&cbuf[v], __ATOMIC_RELAXED, __HIP_MEMORY_SCOPE_AGENT);
  if (t == 0) sred[0] = 0;
  __syncthreads();
  for (int v = t; v < 1024; v += 256) {
    int parent = scomp[v];
    if (parent == v) {
      const unsigned long long key = cl[v];
      if (key != ~0ull) {
        const int lo = (int)((key >> 10) & 1023), hi = (int)(key & 1023);
        const int clo = scomp[lo], chi = scomp[hi];
        const int other = (clo == v) ? chi : clo;
        const bool mutual = (cl[other] == key);
        if (record && (!mutual || v < other)) {
          const int pos = atomicAdd(scnt, 1);
          sdeaths[pos] = __uint_as_float((unsigned int)(key >> 32));
        }
        parent = (mutual && v < other) ? v : other;
      }
    }
    pnew[v] = parent;
  }
  __syncthreads();
#pragma unroll
  for (int it = 0; it < 2; ++it) {
    int q0 = pnew[pnew[t]];
    int q1 = pnew[pnew[t + 256]];
    int q2 = pnew[pnew[t + 512]];
    int q3 = pnew[pnew[t + 768]];
    __syncthreads();
    pnew[t] = q0; pnew[t + 256] = q1; pnew[t + 512] = q2; pnew[t + 768] = q3;
    __syncthreads();
  }
  int nroots = 0;
#pragma unroll
  for (int q = 0; q < 4; ++q) {
    const int v = t + q * 256;
    int p = pnew[v];
    while (p != pnew[p]) p = pnew[p];
    scomp[v] = p;
    if (p == v) ++nroots;
  }
  atomicAdd(&sred[0], nroots);
  __syncthreads();
  return sred[0];
}

__global__ __launch_bounds__(256) void mst_kernel(float* __restrict__ dist,
                                                  unsigned long long* __restrict__ cminb,
                                                  const float* __restrict__ partials,
                                                  float* __restrict__ out) {
  __shared__ int scomp[1024];
  __shared__ int pnew[1024];
  __shared__ unsigned long long cl[1024];
  __shared__ float sdeaths[1023];
  __shared__ int sred[2];              // [0] root count, [1] death count
  __shared__ float redf[12];
  const int t = threadIdx.x;
  const int b = blockIdx.x;
  const bool rec = (b == 0);
  int* slots = (int*)dist;             // slot b at diag (16b+1, 16b+1)

  for (int v = t; v < 1024; v += 256) scomp[v] = v;
  if (t == 0) sred[1] = 0;
  if (t < 16)                          // init buf2 slice (sq overlay is dead)
    __hip_atomic_store(&cminb[2048 + b * 16 + t], ~0ull,
                       __ATOMIC_RELAXED, __HIP_MEMORY_SCOPE_AGENT);
  __syncthreads();

  int ncomp = phase_b_dev(cminb, scomp, cl, pnew, sred, rec, sdeaths, &sred[1]);

  const int lane = t & 63;
  const int w = t >> 6;
  for (int r = 1; r < 10 && ncomp > 1; ++r) {
    unsigned long long* cbuf = cminb + (r % 3) * 1024;
    // ---- phase A: 16 rows per block (4 waves x 4 rows) ----
#pragma unroll
    for (int q = 0; q < 4; ++q) {
      const int i = b * 16 + w * 4 + q;
      const int ci = scomp[i];
      const float* row = dist + i * 1024;
      unsigned long long best = ~0ull;
#pragma unroll
      for (int k = 0; k < 4; ++k) {
        const int j0 = lane * 4 + k * 256;
        const float4 d4 = *(const float4*)(row + j0);
        const int4 c4 = *(const int4*)(&scomp[j0]);
        const float dv[4] = {d4.x, d4.y, d4.z, d4.w};
        const int cv[4] = {c4.x, c4.y, c4.z, c4.w};
#pragma unroll
        for (int c = 0; c < 4; ++c) {
          if (cv[c] != ci) {
            const int j = j0 + c;
            const int lo = i < j ? i : j;
            const int hi = i + j - lo;
            const unsigned long long key =
                ((unsigned long long)__float_as_uint(dv[c]) << 32)
              | (unsigned long long)((lo << 10) | hi);
            if (key < best) best = key;
          }
        }
      }
#pragma unroll
      for (int off = 32; off; off >>= 1) {
        const unsigned int blo = __shfl_xor((unsigned int)best, off);
        const unsigned int bhi = __shfl_xor((unsigned int)(best >> 32), off);
        const unsigned long long o = ((unsigned long long)bhi << 32) | blo;
        if (o < best) best = o;
      }
      if (lane == 0 && best != ~0ull) {
        const unsigned long long cur =
            __hip_atomic_load(&cbuf[ci], __ATOMIC_RELAXED, __HIP_MEMORY_SCOPE_AGENT);
        if (best < cur) atomicMin(&cbuf[ci], best);
      }
    }
    // ---- barrier r: parallel slot stores + wave-0 gather poll ----
    __syncthreads();                   // all waves' atomicMins issued+drained
    if (t == 0)
      __hip_atomic_store(&slots[(size_t)(16 * b + 1) * 1025], r,
                         __ATOMIC_RELEASE, __HIP_MEMORY_SCOPE_AGENT);
    if (t < 64) {
      const size_t sidx = (size_t)(16 * t + 1) * 1025;
      for (;;) {
        const int v = __hip_atomic_load(&slots[sidx], __ATOMIC_ACQUIRE,
                                        __HIP_MEMORY_SCOPE_AGENT);
        if (__all(v >= r)) break;
        __builtin_amdgcn_s_sleep(1);
      }
    }
    __syncthreads();
    // reset previous round's buffer slice (reused in round r+2; race-free:
    // all blocks passed barrier r => all finished phase B of r-1)
    if (t < 16)
      __hip_atomic_store(&cminb[((r - 1) % 3) * 1024 + b * 16 + t], ~0ull,
                         __ATOMIC_RELAXED, __HIP_MEMORY_SCOPE_AGENT);
    ncomp = phase_b_dev(cbuf, scomp, cl, pnew, sred, rec, sdeaths, &sred[1]);
  }

  // ---------------- tail: silhouette + final (block 0 only) ----------------
  if (b != 0) return;
  float lmax = 0.f, lsum = 0.f;
  for (int v = t; v < 1023; v += 256) {
    const float d = sdeaths[v];
    lmax = fmaxf(lmax, d);
    lsum += d;
  }
#pragma unroll
  for (int off = 32; off; off >>= 1) {
    lmax = fmaxf(lmax, __shfl_xor(lmax, off));
    lsum += __shfl_xor(lsum, off);
  }
  if ((t & 63) == 0) { redf[t >> 6] = lmax; redf[4 + (t >> 6)] = lsum; }
  __syncthreads();
  const float tmax = fmaxf(fmaxf(redf[0], redf[1]), fmaxf(redf[2], redf[3]));
  const float wsum = redf[4] + redf[5] + redf[6] + redf[7];
  const float tt = (float)t * (1.0f / 255.0f) * tmax;
  float acc = 0.f;
  for (int j = 0; j < 1023; ++j) {
    const float dj = sdeaths[j];
    acc += dj * fmaxf(fminf(tt, dj - tt), 0.f);
  }
  float phi = acc / (wsum + 1e-12f);
  float rs = 0.f, ks = 0.f;
  for (int v = t; v < 1024; v += 256) { rs += partials[v]; ks += partials[1024 + v]; }
#pragma unroll
  for (int off = 32; off; off >>= 1) {
    phi += __shfl_xor(phi, off);
    rs += __shfl_xor(rs, off);
    ks += __shfl_xor(ks, off);
  }
  __syncthreads();
  if ((t & 63) == 0) { redf[t >> 6] = phi; redf[4 + (t >> 6)] = rs; redf[8 + (t >> 6)] = ks; }
  __syncthreads();
  if (t == 0) {
    const float topo = (redf[0] + redf[1] + redf[2] + redf[3]) * (1.f / 256.f);
    const float recon = (redf[4] + redf[5] + redf[6] + redf[7]) * (1.f / 16777216.f);
    const float kl = -0.5f * (redf[8] + redf[9] + redf[10] + redf[11]) * (1.f / 262144.f);
    const float total = recon + 0.1f * kl + 0.5f * topo;
    out[0] = (float)__float2bfloat16(total);
    out[1] = (float)__float2bfloat16(recon);
    out[2] = (float)__float2bfloat16(kl);
    out[3] = (float)__float2bfloat16(topo);
  }
}

extern "C" void kernel_launch(void* const* d_in, const int* in_sizes, int n_in,
                              void* d_out, int out_size, void* d_ws, size_t ws_size,
                              hipStream_t stream) {
  const float* rx = (const float*)d_in[0];
  const float* x  = (const float*)d_in[1];
  const float* mu = (const float*)d_in[2];
  const float* lv = (const float*)d_in[3];
  const float* z  = (const float*)d_in[4];

  float* wsf = (float*)d_ws;
  unsigned long long* cminb = (unsigned long long*)wsf;    // 3 x u64[1024]
  float* sq       = wsf + 4096;                            // overlays cmin buf2
  float* partials = wsf + 6144;                            // 2048 floats
  float* dist     = wsf + 8192;                            // 4 MB
  float* out      = (float*)d_out;

  losses_kernel<<<NBLK, 512, 0, stream>>>((const float4*)rx, (const float4*)x,
                                          (const float4*)mu, (const float4*)lv,
                                          z, partials, sq, cminb);
  dist_kernel<<<256, 256, 0, stream>>>(z, sq, dist, cminb);
  mst_kernel<<<PBLK, 256, 0, stream>>>(dist, cminb, partials, out);
}